// Round 4
// baseline (1092.501 us; speedup 1.0000x reference)
//
#include <hip/hip_runtime.h>
#include <math.h>

// ---- problem constants ----
#define BSZ 16
#define NV 7
#define CTX 1536
#define PN 192
#define PLEN 16
#define STRIDE 8
#define D 512
#define H 8
#define DK 64
#define DFF 2048
#define LYR 3
#define TW 336
#define NB 112            // B = BSZ*NV
#define RTOT (NB * PN)    // 21504 rows
#define NF (D * PN)       // 98304
#define SCALE 0.125f

typedef __attribute__((ext_vector_type(8))) short s16x8;
typedef __attribute__((ext_vector_type(4))) short s16x4;
typedef __attribute__((ext_vector_type(4))) float f32x4;

__device__ __forceinline__ unsigned short f2b(float f) {
  unsigned u = __builtin_bit_cast(unsigned, f);
  u = u + 0x7fffu + ((u >> 16) & 1u);
  return (unsigned short)(u >> 16);
}
__device__ __forceinline__ float b2f(unsigned short h) {
  unsigned u = ((unsigned)h) << 16;
  return __builtin_bit_cast(float, u);
}
// pack 2 f32 -> 2 bf16 in one dword (RNE), one instruction
__device__ __forceinline__ unsigned cvtpk(float lo, float hi) {
  unsigned r;
  asm("v_cvt_pk_bf16_f32 %0, %1, %2" : "=v"(r) : "v"(lo), "v"(hi));
  return r;
}
__device__ __forceinline__ float fast_exp2(float x) {
  float r; asm("v_exp_f32 %0, %1" : "=v"(r) : "v"(x)); return r;
}
__device__ __forceinline__ float fast_rcp(float x) {
  float r; asm("v_rcp_f32 %0, %1" : "=v"(r) : "v"(x)); return r;
}

// async global->LDS, 16B per lane, dest = wave-uniform base + lane*16
__device__ __forceinline__ void glld(const unsigned short* g, short* l) {
  __builtin_amdgcn_global_load_lds(
      (const __attribute__((address_space(1))) void*)g,
      (__attribute__((address_space(3))) void*)l, 16, 0, 0);
}

// tanh-form GELU, folded: gelu = x*w/(w+1), w = exp2(a*x + b*x^3)
__device__ __forceinline__ float gelu(float x) {
  float x2 = x * x;
  float u2 = x * fmaf(0.1029492f, x2, 2.3021186f);
  u2 = fminf(fmaxf(u2, -60.f), 60.f);
  float w = fast_exp2(u2);
  return x * w * fast_rcp(w + 1.0f);
}

// ---------------------------------------------------------------------------
// patch embed -> bf16 state s
// ---------------------------------------------------------------------------
__global__ __launch_bounds__(256) void k_patch_embed(
    const float* __restrict__ z, const float* __restrict__ W_P,
    const float* __restrict__ b_P, const float* __restrict__ W_pos,
    unsigned short* __restrict__ s) {
  int r = blockIdx.x;
  int bi = r / PN, p = r % PN;
  __shared__ float pv[PLEN];
  if (threadIdx.x < PLEN) {
    int t = p * STRIDE + threadIdx.x;
    pv[threadIdx.x] = z[(size_t)bi * CTX + (t < CTX ? t : CTX - 1)];
  }
  __syncthreads();
  for (int c = threadIdx.x; c < D; c += 256) {
    float acc = b_P[c] + W_pos[p * D + c];
#pragma unroll
    for (int j = 0; j < PLEN; j++) acc += pv[j] * W_P[j * D + c];
    s[(size_t)r * D + c] = f2b(acc);
  }
}

// ---------------------------------------------------------------------------
// batched weight transpose + bf16 pack: Wt[n][k] = bf16(W[k][n]), z = layer.
// ---------------------------------------------------------------------------
__global__ __launch_bounds__(256) void k_wtz(
    const float* __restrict__ W, unsigned short* __restrict__ Wt, int K, int N,
    size_t sstride, size_t dstride) {
  __shared__ float tile[32][33];
  const float* Wz = W + (size_t)blockIdx.z * sstride;
  unsigned short* Wtz = Wt + (size_t)blockIdx.z * dstride;
  int n0 = blockIdx.x * 32, k0 = blockIdx.y * 32;
  int tx = threadIdx.x & 31, ty = threadIdx.x >> 5;
#pragma unroll
  for (int i = 0; i < 4; i++)
    tile[ty + 8 * i][tx] =
        (n0 + tx < N) ? Wz[(size_t)(k0 + ty + 8 * i) * N + n0 + tx] : 0.0f;
  __syncthreads();
#pragma unroll
  for (int i = 0; i < 4; i++)
    if (n0 + ty + 8 * i < N)
      Wtz[(size_t)(n0 + ty + 8 * i) * K + k0 + tx] = f2b(tile[tx][ty + 8 * i]);
}

// ---------------------------------------------------------------------------
// bf16 MFMA GEMM: out = epi(A[M,K] @ Wt[N,K]^T + bias), N/K compile-time.
// 128x256 block tile, 4 waves (2M x 2N), wave tile 64x128 (4x8 16x16 frags).
// Rationale (r3 counters): wall ~= MFMA(52k) + LDS-read(64k) + VALU(54k) per
// CU, i.e. pipes nearly serialized and LDS reads dominate. 64x128 wave tile
// cuts ds_reads/FLOP by 25% (12 reads / 32 MFMA per step vs 8/16), halves
// barriers+loop VALU per FLOP, halves block count (prologue/epilogue amort).
// BK=32, 3-deep LDS ring (3 x 24 KB = 72 KB) with counted vmcnt(12): slot s
// staged 2 steps ahead (6 glld/wave/step), never drained mid-loop. Bank-safe
// 4-slot swizzle: slot = lq ^ ((lr>>1)&3). Swapped-operand MFMA; epilogue
// cvt_pk -> swizzled LDS C-tile -> 16B stores. 1D grid with XCD swizzle.
// ---------------------------------------------------------------------------
enum { EPI_QKV = 0, EPI_RES = 1, EPI_GELU = 2 };

template <int EPI, int N, int K>
__global__ __launch_bounds__(256, 2) void k_mgemm(
    const unsigned short* __restrict__ Ap, const unsigned short* __restrict__ Wt,
    const float* __restrict__ bias0, const float* __restrict__ bias1,
    const float* __restrict__ bias2, const unsigned short* __restrict__ res,
    unsigned short* __restrict__ out0, unsigned short* __restrict__ out1,
    unsigned short* __restrict__ out2) {
  __shared__ short smem[36864];  // 72 KB: ring buf b at b*12288 (A 4096 | B 8192)
  constexpr int NSTEP = K / 32;
  const int nx = N >> 8;
  const int nwg = gridDim.x;
  const int orig = blockIdx.x;
  const int wgid = (orig & 7) * (nwg >> 3) + (orig >> 3);  // nwg % 8 == 0
  const int m0 = (wgid / nx) * 128, n0 = (wgid % nx) * 256;
  const int t = threadIdx.x;
  const int w = t >> 6, l = t & 63;
  const int wr = (w >> 1) * 64, wc = (w & 1) * 128;
  const int lr = l & 15, lq = l >> 4;
  const int rsw = ((lr >> 1) & 3) << 3;             // read-side XOR (shorts)
  const int scol = 8 * ((l & 3) ^ ((l >> 3) & 3));  // pre-swizzled source col
  const int srA = w * 32 + (l >> 2);                // A staging row (2 glld)
  const int srB = w * 64 + (l >> 2);                // B staging row (4 glld)
  const unsigned short* gA = Ap + (size_t)(m0 + srA) * K + scol;
  const unsigned short* gB = Wt + (size_t)(n0 + srB) * K + scol;
  f32x4 acc[4][8] = {};

  auto STAGE = [&](int b, int kt) {
    short* dA = &smem[b * 12288 + (w * 32) * 32];
    short* dB = &smem[b * 12288 + 4096 + (w * 64) * 32];
    const int k0 = kt * 32;
    glld(gA + k0, dA);
    glld(gA + k0 + (size_t)16 * K, dA + 512);
    glld(gB + k0, dB);
    glld(gB + k0 + (size_t)16 * K, dB + 512);
    glld(gB + k0 + (size_t)32 * K, dB + 1024);
    glld(gB + k0 + (size_t)48 * K, dB + 1536);
  };

  STAGE(0, 0);
  STAGE(1, 1);
  int bc = 0, bs = 2;
  for (int step = 0; step < NSTEP; step++) {
    if (step + 2 < NSTEP) STAGE(bs, step + 2);
    // wait until slot `step%3`'s 6 loads retired (FIFO): newer stay in flight
    if (step + 2 < NSTEP)      asm volatile("s_waitcnt vmcnt(12)" ::: "memory");
    else if (step + 1 < NSTEP) asm volatile("s_waitcnt vmcnt(6)" ::: "memory");
    else                       asm volatile("s_waitcnt vmcnt(0)" ::: "memory");
    __builtin_amdgcn_s_barrier();
    const short* cA = &smem[bc * 12288];
    const short* cB = &smem[bc * 12288 + 4096];
    s16x8 af[4], bf[8];
#pragma unroll
    for (int i = 0; i < 4; i++)
      af[i] = *(const s16x8*)&cA[(wr + i * 16 + lr) * 32 + ((lq * 8) ^ rsw)];
#pragma unroll
    for (int j = 0; j < 8; j++)
      bf[j] = *(const s16x8*)&cB[(wc + j * 16 + lr) * 32 + ((lq * 8) ^ rsw)];
#pragma unroll
    for (int i = 0; i < 4; i++)
#pragma unroll
      for (int j = 0; j < 8; j++)
        acc[i][j] = __builtin_amdgcn_mfma_f32_16x16x32_bf16(bf[j], af[i], acc[i][j], 0, 0, 0);
    // drain this wave's LDS reads before anyone overwrites this ring slot
    asm volatile("s_waitcnt lgkmcnt(0)" ::: "memory");
    __builtin_amdgcn_s_barrier();
    bc++; if (bc == 3) bc = 0;
    bs++; if (bs == 3) bs = 0;
  }

  // ---- epilogue. swapped D map: row ml = wr+i*16+lr, cols nl = wc+j*16+lq*4+r
  short* ot = smem;  // 128 x 256 bf16 C staging (64 KB of 72)
  if (EPI == EPI_QKV) {
    const int which = n0 >> 9;  // 256-wide tile sits inside one 512 region
    const int ccb = n0 & 511;
    const float* bias = (which == 0) ? bias0 : (which == 1) ? bias1 : bias2;
    unsigned short* dst = (which == 0) ? out0 : (which == 1) ? out1 : out2;
    if (which < 2) {
      // Q/K: LDS-staged fast path with [bh][p][dk] remapped 16B stores
#pragma unroll
      for (int i = 0; i < 4; i++) {
        const int ml = wr + i * 16 + lr;
#pragma unroll
        for (int j2 = 0; j2 < 8; j2++) {
          const int nl = wc + j2 * 16 + lq * 4;
          f32x4 a = acc[i][j2];
          float4 b4 = *(const float4*)&bias[ccb + nl];
          unsigned lo = cvtpk(a[0] + b4.x, a[1] + b4.y);
          unsigned hi = cvtpk(a[2] + b4.z, a[3] + b4.w);
          unsigned* d = (unsigned*)&ot[ml * 256 + ((nl >> 3) ^ (ml & 15)) * 8 + (nl & 7)];
          d[0] = lo; d[1] = hi;
        }
      }
      __syncthreads();
      const int r0 = t >> 1, cb = (t & 1) * 16;
      const int m = m0 + r0;
      const int bi2 = m / PN, p = m % PN;
#pragma unroll
      for (int q = 0; q < 16; q++) {
        int c = cb + q;
        int cc = ccb + c * 8;
        int hh = cc >> 6, dk8 = cc & 63;
        s16x8 vv = *(const s16x8*)&ot[r0 * 256 + ((c ^ (r0 & 15)) * 8)];
        *(s16x8*)&dst[(((size_t)bi2 * H + hh) * PN + p) * DK + dk8] = vv;
      }
    } else {
      // V: transposed per-head [bh][dk][p] scatter (16-lane p-contiguous)
#pragma unroll
      for (int i = 0; i < 4; i++) {
        const int m = m0 + wr + i * 16 + lr;
        const int bi2 = m / PN, p = m % PN;
#pragma unroll
        for (int j2 = 0; j2 < 8; j2++) {
          const int nl = wc + j2 * 16 + lq * 4;
          f32x4 a = acc[i][j2];
#pragma unroll
          for (int r = 0; r < 4; r++) {
            int cc = ccb + nl + r;
            int hh = cc >> 6, dkk = cc & 63;
            dst[(((size_t)bi2 * H + hh) * DK + dkk) * PN + p] = f2b(a[r] + bias[cc]);
          }
        }
      }
    }
  } else {
#pragma unroll
    for (int i = 0; i < 4; i++) {
      const int ml = wr + i * 16 + lr;
#pragma unroll
      for (int j2 = 0; j2 < 8; j2++) {
        const int nl = wc + j2 * 16 + lq * 4;
        f32x4 a = acc[i][j2];
        float4 b4 = *(const float4*)&bias0[n0 + nl];
        float v0 = a[0] + b4.x, v1 = a[1] + b4.y;
        float v2 = a[2] + b4.z, v3 = a[3] + b4.w;
        if (EPI == EPI_GELU) {
          v0 = gelu(v0); v1 = gelu(v1); v2 = gelu(v2); v3 = gelu(v3);
        } else {  // EPI_RES
          s16x4 rr = *(const s16x4*)&res[(size_t)(m0 + ml) * N + n0 + nl];
          v0 += b2f((unsigned short)rr[0]); v1 += b2f((unsigned short)rr[1]);
          v2 += b2f((unsigned short)rr[2]); v3 += b2f((unsigned short)rr[3]);
        }
        unsigned lo = cvtpk(v0, v1), hi = cvtpk(v2, v3);
        unsigned* d = (unsigned*)&ot[ml * 256 + ((nl >> 3) ^ (ml & 15)) * 8 + (nl & 7)];
        d[0] = lo; d[1] = hi;
      }
    }
    __syncthreads();
    const int r0 = t >> 1, cb = (t & 1) * 16;
    const size_t orow = (size_t)(m0 + r0) * N + n0;
#pragma unroll
    for (int q = 0; q < 16; q++) {
      int c = cb + q;
      s16x8 vv = *(const s16x8*)&ot[r0 * 256 + ((c ^ (r0 & 15)) * 8)];
      *(s16x8*)&out0[orow + c * 8] = vv;
    }
  }
}

// ---------------------------------------------------------------------------
// fused attention: scores (+carry,+dm) -> carry write -> softmax -> PV -> O.
// Grid = NB*H*2 (bh = blk>>1, q-half = blk&1), 256 threads = 4 waves (2q x 2k).
// ---------------------------------------------------------------------------
#define PSTR 196
template <int FIRST, int WRITEC>
__global__ __launch_bounds__(256) void k_attn(
    const unsigned short* __restrict__ qb, const unsigned short* __restrict__ kb,
    const unsigned short* __restrict__ vt, const float* __restrict__ dm,
    unsigned short* __restrict__ carry, unsigned short* __restrict__ ob) {
  __shared__ short Ps[96 * PSTR];     // 37.6 KB, unnormalized exp (bf16)
  __shared__ float redmax[2][96];
  __shared__ float redsum[2][96];
  int blk = blockIdx.x;
  int bh = blk >> 1, qh = blk & 1;
  int bi = bh >> 3, h = bh & 7;
  int t = threadIdx.x, w = t >> 6, l = t & 63;
  int wq = w >> 1, wk = w & 1;
  int lr = l & 15, lq = l >> 4, lk = lq * 8;
  const unsigned short* Q = qb + (size_t)bh * PN * DK + (size_t)qh * 96 * DK;
  const unsigned short* K = kb + (size_t)bh * PN * DK;
  f32x4 sv[3][6] = {};
#pragma unroll
  for (int ks = 0; ks < 2; ks++) {
    s16x8 af[3], bf[6];
#pragma unroll
    for (int i = 0; i < 3; i++)
      af[i] = *(const s16x8*)&Q[(size_t)(wq * 48 + i * 16 + lr) * DK + ks * 32 + lk];
#pragma unroll
    for (int j = 0; j < 6; j++)
      bf[j] = *(const s16x8*)&K[(size_t)(wk * 96 + j * 16 + lr) * DK + ks * 32 + lk];
#pragma unroll
    for (int i = 0; i < 3; i++)
#pragma unroll
      for (int j = 0; j < 6; j++)
        sv[i][j] = __builtin_amdgcn_mfma_f32_16x16x32_bf16(af[i], bf[j], sv[i][j], 0, 0, 0);
  }
  size_t cbase = (size_t)blk * 18432 + (size_t)(w * 18) * 256 + (size_t)l * 4;
#pragma unroll
  for (int i = 0; i < 3; i++) {
#pragma unroll
    for (int j = 0; j < 6; j++) {
      s16x4 cv;
      if (!FIRST) cv = *(const s16x4*)&carry[cbase + (i * 6 + j) * 256];
      s16x4 cw;
#pragma unroll
      for (int r = 0; r < 4; r++) {
        int row = qh * 96 + wq * 48 + i * 16 + lq * 4 + r;
        int col = wk * 96 + j * 16 + lr;
        float v = sv[i][j][r] * SCALE + dm[row * PN + col];
        if (!FIRST) v += b2f((unsigned short)cv[r]);
        if (WRITEC) cw[r] = (short)f2b(v);
        sv[i][j][r] = v;
      }
      if (WRITEC) *(s16x4*)&carry[cbase + (i * 6 + j) * 256] = cw;
    }
  }
#pragma unroll
  for (int i = 0; i < 3; i++) {
#pragma unroll
    for (int r = 0; r < 4; r++) {
      float m = sv[i][0][r];
#pragma unroll
      for (int j = 1; j < 6; j++) m = fmaxf(m, sv[i][j][r]);
#pragma unroll
      for (int off = 1; off < 16; off <<= 1) m = fmaxf(m, __shfl_xor(m, off));
      if (lr == 0) redmax[wk][wq * 48 + i * 16 + lq * 4 + r] = m;
    }
  }
  __syncthreads();
#pragma unroll
  for (int i = 0; i < 3; i++) {
#pragma unroll
    for (int r = 0; r < 4; r++) {
      int row = wq * 48 + i * 16 + lq * 4 + r;
      float fm = fmaxf(redmax[0][row], redmax[1][row]);
      float sum = 0.f;
#pragma unroll
      for (int j = 0; j < 6; j++) {
        float e = __expf(sv[i][j][r] - fm);
        sum += e;
        Ps[row * PSTR + wk * 96 + j * 16 + lr] = f2b(e);
      }
#pragma unroll
      for (int off = 1; off < 16; off <<= 1) sum += __shfl_xor(sum, off);
      if (lr == 0) redsum[wk][row] = sum;
    }
  }
  __syncthreads();
  const unsigned short* V = vt + (size_t)bh * DK * PN;
  f32x4 po[3][2] = {};
#pragma unroll
  for (int ks = 0; ks < 6; ks++) {
    s16x8 af[3], bf[2];
#pragma unroll
    for (int i = 0; i < 3; i++)
      af[i] = *(const s16x8*)&Ps[(wq * 48 + i * 16 + lr) * PSTR + ks * 32 + lk];
#pragma unroll
    for (int j = 0; j < 2; j++)
      bf[j] = *(const s16x8*)&V[(size_t)(wk * 32 + j * 16 + lr) * PN + ks * 32 + lk];
#pragma unroll
    for (int i = 0; i < 3; i++)
#pragma unroll
      for (int j = 0; j < 2; j++)
        po[i][j] = __builtin_amdgcn_mfma_f32_16x16x32_bf16(af[i], bf[j], po[i][j], 0, 0, 0);
  }
#pragma unroll
  for (int i = 0; i < 3; i++) {
#pragma unroll
    for (int r = 0; r < 4; r++) {
      int row = wq * 48 + i * 16 + lq * 4 + r;
      float inv = 1.0f / (redsum[0][row] + redsum[1][row]);
#pragma unroll
      for (int j = 0; j < 2; j++) {
        int dk = wk * 32 + j * 16 + lr;
        ob[((size_t)bi * PN + qh * 96 + row) * D + h * 64 + dk] = f2b(po[i][j][r] * inv);
      }
    }
  }
}

// ---------------------------------------------------------------------------
// LayerNorm: bf16 in -> bf16 out. One wave per row, s16x8 I/O (16B/lane).
// ---------------------------------------------------------------------------
__global__ __launch_bounds__(256) void k_ln(
    const unsigned short* __restrict__ in, const float* __restrict__ g,
    const float* __restrict__ b, unsigned short* __restrict__ out) {
  int r = blockIdx.x * 4 + (threadIdx.x >> 6);
  int l = threadIdx.x & 63;
  const unsigned short* x = in + (size_t)r * D + l * 8;
  s16x8 xv = *(const s16x8*)x;
  float v[8], sm = 0.f, sq = 0.f;
#pragma unroll
  for (int j = 0; j < 8; j++) {
    v[j] = b2f((unsigned short)xv[j]);
    sm += v[j];
    sq += v[j] * v[j];
  }
#pragma unroll
  for (int off = 32; off > 0; off >>= 1) {
    sm += __shfl_xor(sm, off);
    sq += __shfl_xor(sq, off);
  }
  float mu = sm * (1.0f / D);
  float rs = rsqrtf(sq * (1.0f / D) - mu * mu + 1e-5f);
  float4 g0 = *(const float4*)&g[l * 8], g1 = *(const float4*)&g[l * 8 + 4];
  float4 b0 = *(const float4*)&b[l * 8], b1 = *(const float4*)&b[l * 8 + 4];
  float gg[8] = {g0.x, g0.y, g0.z, g0.w, g1.x, g1.y, g1.z, g1.w};
  float bb[8] = {b0.x, b0.y, b0.z, b0.w, b1.x, b1.y, b1.z, b1.w};
  s16x8 ov;
#pragma unroll
  for (int j = 0; j < 8; j++) ov[j] = (short)f2b(gg[j] * (v[j] - mu) * rs + bb[j]);
  *(s16x8*)(out + (size_t)r * D + l * 8) = ov;
}

// ---------------------------------------------------------------------------
// head input transpose (bf16): xo[bv][d*PN+p] = s[bv*PN+p][d]
// ---------------------------------------------------------------------------
__global__ __launch_bounds__(256) void k_transpose_b(
    const unsigned short* __restrict__ sb, unsigned short* __restrict__ xo) {
  __shared__ unsigned short tile[32][33];
  int d0 = blockIdx.x * 32, p0 = blockIdx.y * 32, bv = blockIdx.z;
  int tx = threadIdx.x & 31, ty = threadIdx.x >> 5;
#pragma unroll
  for (int i = 0; i < 4; i++)
    tile[ty + 8 * i][tx] = sb[((size_t)bv * PN + p0 + ty + 8 * i) * D + d0 + tx];
  __syncthreads();
#pragma unroll
  for (int i = 0; i < 4; i++)
    xo[(size_t)bv * NF + (size_t)(d0 + ty + 8 * i) * PN + p0 + tx] = tile[tx][ty + 8 * i];
}

// ---------------------------------------------------------------------------
// head MFMA GEMM, split-K partials
// ---------------------------------------------------------------------------
__global__ __launch_bounds__(448) void k_head_mgemm(
    const unsigned short* __restrict__ A, const unsigned short* __restrict__ B,
    float* __restrict__ pp) {
  __shared__ short As[112 * 40];
  __shared__ short Bs[336 * 40];
  int kc = blockIdx.x;
  int t = threadIdx.x, w = t >> 6, l = t & 63;
  int lr = l & 15, lk = (l >> 4) * 8;
  int ar = t >> 2, ac = (t & 3) * 8;
  f32x4 acc[7][3] = {};
  for (int ks = 0; ks < 24; ks++) {
    int k0 = kc * 768 + ks * 32;
    s16x8 av = *(const s16x8*)&A[(size_t)ar * NF + k0 + ac];
    s16x8 bv0, bv1, bv2;
    {
      int i0 = t, i1 = t + 448, i2 = t + 896;
      bv0 = *(const s16x8*)&B[(size_t)(i0 >> 2) * NF + k0 + (i0 & 3) * 8];
      bv1 = *(const s16x8*)&B[(size_t)(i1 >> 2) * NF + k0 + (i1 & 3) * 8];
      bv2 = *(const s16x8*)&B[(size_t)(i2 >> 2) * NF + k0 + (i2 & 3) * 8];
    }
    __syncthreads();
    *(s16x8*)&As[ar * 40 + ac] = av;
    *(s16x8*)&Bs[(t >> 2) * 40 + (t & 3) * 8] = bv0;
    *(s16x8*)&Bs[((t + 448) >> 2) * 40 + (t & 3) * 8] = bv1;
    *(s16x8*)&Bs[((t + 896) >> 2) * 40 + (t & 3) * 8] = bv2;
    __syncthreads();
    s16x8 bf[3];
#pragma unroll
    for (int j = 0; j < 3; j++)
      bf[j] = *(const s16x8*)&Bs[((w * 3 + j) * 16 + lr) * 40 + lk];
#pragma unroll
    for (int mf = 0; mf < 7; mf++) {
      s16x8 af = *(const s16x8*)&As[(mf * 16 + lr) * 40 + lk];
#pragma unroll
      for (int j = 0; j < 3; j++)
        acc[mf][j] = __builtin_amdgcn_mfma_f32_16x16x32_bf16(af, bf[j], acc[mf][j], 0, 0, 0);
    }
  }
#pragma unroll
  for (int mf = 0; mf < 7; mf++) {
#pragma unroll
    for (int j = 0; j < 3; j++) {
#pragma unroll
      for (int r = 0; r < 4; r++) {
        int row = mf * 16 + (l >> 4) * 4 + r;
        int col = (w * 3 + j) * 16 + lr;
        pp[((size_t)kc * NB + row) * TW + col] = acc[mf][j][r];
      }
    }
  }
}

__global__ __launch_bounds__(256) void k_head_reduce(
    const float* __restrict__ pp, const float* __restrict__ bh,
    float* __restrict__ out) {
  int i = blockIdx.x * 256 + threadIdx.x;
  float s = bh[i % TW];
  for (int kc = 0; kc < 128; kc++) s += pp[(size_t)kc * (NB * TW) + i];
  out[i] = s;
}

// ---------------------------------------------------------------------------
extern "C" void kernel_launch(void* const* d_in, const int* in_sizes, int n_in,
                              void* d_out, int out_size, void* d_ws, size_t ws_size,
                              hipStream_t stream) {
  const float* z     = (const float*)d_in[0];
  const float* W_P   = (const float*)d_in[1];
  const float* b_P   = (const float*)d_in[2];
  const float* W_pos = (const float*)d_in[3];
  const float* Wq    = (const float*)d_in[4];
  const float* bq    = (const float*)d_in[5];
  const float* Wk    = (const float*)d_in[6];
  const float* bk    = (const float*)d_in[7];
  const float* Wv    = (const float*)d_in[8];
  const float* bv    = (const float*)d_in[9];
  const float* Wo    = (const float*)d_in[10];
  const float* bo    = (const float*)d_in[11];
  const float* ln1g  = (const float*)d_in[12];
  const float* ln1b  = (const float*)d_in[13];
  const float* W1    = (const float*)d_in[14];
  const float* b1    = (const float*)d_in[15];
  const float* W2    = (const float*)d_in[16];
  const float* b2    = (const float*)d_in[17];
  const float* ln2g  = (const float*)d_in[18];
  const float* ln2b  = (const float*)d_in[19];
  const float* Wh    = (const float*)d_in[20];
  const float* bh    = (const float*)d_in[21];
  const float* dmask = (const float*)d_in[22];
  float* out = (float*)d_out;

  // ---- workspace layout (bytes), extent 217,055,232 ----
  char* ws = (char*)d_ws;
  unsigned short* s  = (unsigned short*)ws;
  unsigned short* sc = (unsigned short*)(ws + 22020096ull);
  unsigned short* qb = (unsigned short*)(ws + 88080384ull);
  unsigned short* kb = (unsigned short*)(ws + 110100480ull);
  unsigned short* vb = (unsigned short*)(ws + 132120576ull);
  unsigned short* ob = (unsigned short*)(ws + 154140672ull);
  unsigned short* tb = (unsigned short*)(ws + 176160768ull);
  unsigned short* hb = qb;                       // 88MB (qb..ob), post-attention
  unsigned short* t2 = tb;                       // FFN out reuses tb region
  unsigned short* wt = (unsigned short*)(ws + 198180864ull);
  const size_t WLS = 3145728;  // shorts per layer block
  // head-phase reuse:
  unsigned short* xo  = (unsigned short*)(ws + 88080384ull);   // [112][98304]
  unsigned short* Wht = (unsigned short*)(ws + 110100480ull);  // [336][98304]
  float* pp = (float*)(ws + 22020096ull);                      // [128][112][336]

  k_patch_embed<<<RTOT, 256, 0, stream>>>(z, W_P, b_P, W_pos, s);

  // pre-loop batched weight transposes (z = layer)
  k_wtz<<<dim3(16, 16, 3), 256, 0, stream>>>(Wq, wt + 0,       D, D,   262144, WLS);
  k_wtz<<<dim3(16, 16, 3), 256, 0, stream>>>(Wk, wt + 262144,  D, D,   262144, WLS);
  k_wtz<<<dim3(16, 16, 3), 256, 0, stream>>>(Wv, wt + 524288,  D, D,   262144, WLS);
  k_wtz<<<dim3(16, 16, 3), 256, 0, stream>>>(Wo, wt + 786432,  D, D,   262144, WLS);
  k_wtz<<<dim3(64, 16, 3), 256, 0, stream>>>(W1, wt + 1048576, D, DFF, 1048576, WLS);
  k_wtz<<<dim3(16, 64, 3), 256, 0, stream>>>(W2, wt + 2097152, DFF, D, 1048576, WLS);

  for (int l = 0; l < LYR; l++) {
    unsigned short* wtL = wt + (size_t)l * WLS;
    unsigned short* wqkv_t = wtL;
    unsigned short* wo_t   = wtL + 786432;
    unsigned short* w1_t   = wtL + 1048576;
    unsigned short* w2_t   = wtL + 2097152;

    // fused QKV GEMM: [21504,512] x [512,1536], 128x256 tiles, grid 168x6 = 1008
    k_mgemm<EPI_QKV, 1536, 512><<<1008, 256, 0, stream>>>(
        s, wqkv_t, bq + l * D, bk + l * D, bv + l * D, nullptr, qb, kb, vb);
    // fused attention (scores + carry + softmax + PV)
    const float* dm = dmask + (size_t)l * PN * PN;
    if (l == 0)
      k_attn<1, 1><<<NB * H * 2, 256, 0, stream>>>(qb, kb, vb, dm, sc, ob);
    else if (l == LYR - 1)
      k_attn<0, 0><<<NB * H * 2, 256, 0, stream>>>(qb, kb, vb, dm, sc, ob);
    else
      k_attn<0, 1><<<NB * H * 2, 256, 0, stream>>>(qb, kb, vb, dm, sc, ob);
    // O-proj + residual: grid 168x2 = 336
    k_mgemm<EPI_RES, 512, 512><<<336, 256, 0, stream>>>(
        ob, wo_t, bo + l * D, nullptr, nullptr, s, tb, nullptr, nullptr);
    k_ln<<<RTOT / 4, 256, 0, stream>>>(tb, ln1g + l * D, ln1b + l * D, s);
    // FFN full-M: W1 grid 168x8 = 1344, W2 grid 168x2 = 336
    k_mgemm<EPI_GELU, 2048, 512><<<1344, 256, 0, stream>>>(
        s, w1_t, b1 + l * DFF, nullptr, nullptr, nullptr, hb, nullptr, nullptr);
    k_mgemm<EPI_RES, 512, 2048><<<336, 256, 0, stream>>>(
        hb, w2_t, b2 + l * D, nullptr, nullptr, s, t2, nullptr, nullptr);
    k_ln<<<RTOT / 4, 256, 0, stream>>>(t2, ln2g + l * D, ln2b + l * D, s);
  }

  // head: pack Wh^T bf16, transpose s -> xo bf16, split-K MFMA, reduce
  k_wtz<<<dim3(11, 3072, 1), 256, 0, stream>>>(Wh, Wht, NF, TW, 0, 0);
  k_transpose_b<<<dim3(16, 6, NB), 256, 0, stream>>>(s, xo);
  k_head_mgemm<<<128, 448, 0, stream>>>(xo, Wht, pp);
  k_head_reduce<<<147, 256, 0, stream>>>(pp, bh, out);
}

// Round 5
// 1062.496 us; speedup vs baseline: 1.0282x; 1.0282x over previous
//
#include <hip/hip_runtime.h>
#include <math.h>

// ---- problem constants ----
#define BSZ 16
#define NV 7
#define CTX 1536
#define PN 192
#define PLEN 16
#define STRIDE 8
#define D 512
#define H 8
#define DK 64
#define DFF 2048
#define LYR 3
#define TW 336
#define NB 112            // B = BSZ*NV
#define RTOT (NB * PN)    // 21504 rows
#define NF (D * PN)       // 98304
#define SCALE 0.125f

typedef __attribute__((ext_vector_type(8))) short s16x8;
typedef __attribute__((ext_vector_type(4))) short s16x4;
typedef __attribute__((ext_vector_type(4))) float f32x4;

__device__ __forceinline__ unsigned short f2b(float f) {
  unsigned u = __builtin_bit_cast(unsigned, f);
  u = u + 0x7fffu + ((u >> 16) & 1u);
  return (unsigned short)(u >> 16);
}
__device__ __forceinline__ float b2f(unsigned short h) {
  unsigned u = ((unsigned)h) << 16;
  return __builtin_bit_cast(float, u);
}
// pack 2 f32 -> 2 bf16 in one dword (RNE), one instruction
__device__ __forceinline__ unsigned cvtpk(float lo, float hi) {
  unsigned r;
  asm("v_cvt_pk_bf16_f32 %0, %1, %2" : "=v"(r) : "v"(lo), "v"(hi));
  return r;
}
__device__ __forceinline__ float fast_exp2(float x) {
  float r; asm("v_exp_f32 %0, %1" : "=v"(r) : "v"(x)); return r;
}
__device__ __forceinline__ float fast_rcp(float x) {
  float r; asm("v_rcp_f32 %0, %1" : "=v"(r) : "v"(x)); return r;
}

// async global->LDS, 16B per lane, dest = wave-uniform base + lane*16
__device__ __forceinline__ void glld(const unsigned short* g, short* l) {
  __builtin_amdgcn_global_load_lds(
      (const __attribute__((address_space(1))) void*)g,
      (__attribute__((address_space(3))) void*)l, 16, 0, 0);
}

// tanh-form GELU, folded: gelu = x*w/(w+1), w = exp2(a*x + b*x^3)
__device__ __forceinline__ float gelu(float x) {
  float x2 = x * x;
  float u2 = x * fmaf(0.1029492f, x2, 2.3021186f);
  u2 = fminf(fmaxf(u2, -60.f), 60.f);
  float w = fast_exp2(u2);
  return x * w * fast_rcp(w + 1.0f);
}

// ---------------------------------------------------------------------------
// patch embed -> bf16 state s
// ---------------------------------------------------------------------------
__global__ __launch_bounds__(256) void k_patch_embed(
    const float* __restrict__ z, const float* __restrict__ W_P,
    const float* __restrict__ b_P, const float* __restrict__ W_pos,
    unsigned short* __restrict__ s) {
  int r = blockIdx.x;
  int bi = r / PN, p = r % PN;
  __shared__ float pv[PLEN];
  if (threadIdx.x < PLEN) {
    int t = p * STRIDE + threadIdx.x;
    pv[threadIdx.x] = z[(size_t)bi * CTX + (t < CTX ? t : CTX - 1)];
  }
  __syncthreads();
  for (int c = threadIdx.x; c < D; c += 256) {
    float acc = b_P[c] + W_pos[p * D + c];
#pragma unroll
    for (int j = 0; j < PLEN; j++) acc += pv[j] * W_P[j * D + c];
    s[(size_t)r * D + c] = f2b(acc);
  }
}

// ---------------------------------------------------------------------------
// batched weight transpose + bf16 pack: Wt[n][k] = bf16(W[k][n]), z = layer.
// ---------------------------------------------------------------------------
__global__ __launch_bounds__(256) void k_wtz(
    const float* __restrict__ W, unsigned short* __restrict__ Wt, int K, int N,
    size_t sstride, size_t dstride) {
  __shared__ float tile[32][33];
  const float* Wz = W + (size_t)blockIdx.z * sstride;
  unsigned short* Wtz = Wt + (size_t)blockIdx.z * dstride;
  int n0 = blockIdx.x * 32, k0 = blockIdx.y * 32;
  int tx = threadIdx.x & 31, ty = threadIdx.x >> 5;
#pragma unroll
  for (int i = 0; i < 4; i++)
    tile[ty + 8 * i][tx] =
        (n0 + tx < N) ? Wz[(size_t)(k0 + ty + 8 * i) * N + n0 + tx] : 0.0f;
  __syncthreads();
#pragma unroll
  for (int i = 0; i < 4; i++)
    if (n0 + ty + 8 * i < N)
      Wtz[(size_t)(n0 + ty + 8 * i) * K + k0 + tx] = f2b(tile[tx][ty + 8 * i]);
}

// ---------------------------------------------------------------------------
// bf16 MFMA GEMM: out = epi(A[M,K] @ Wt[N,K]^T + bias), N/K compile-time.
// 128x128 tile, BK=32, 2-deep LDS double buffer (32 KB) with counted
// vmcnt(4). KEY CHANGE (r5): __launch_bounds__(256, 4) caps the unified
// register budget at 128/wave (64 acc AGPR + <=64 arch VGPR). Theory from
// r0-r4: occupancy was pinned at 8 waves/CU by the 129-256 VGPR bucket
// (m69: waves/CU halves at vgpr={64,128,256}); total 136 regs wasted half
// the residency. <=128 regs + 32 KB LDS -> 4 blocks/CU = 16 waves/CU, and
// co-resident blocks hide each other's barrier/waitcnt stalls (the r3
// serialized-pipes wall). Bank-safe 4-slot swizzle: slot = lq ^ ((lr>>1)&3).
// Swapped-operand MFMA; epilogues via cvt_pk -> swizzled LDS C-tile -> 16B
// stores. 1D grid with XCD swizzle (grid % 8 == 0).
// ---------------------------------------------------------------------------
enum { EPI_QKV = 0, EPI_RES = 1, EPI_GELU = 2 };

template <int EPI, int N, int K>
__global__ __launch_bounds__(256, 4) void k_mgemm(
    const unsigned short* __restrict__ Ap, const unsigned short* __restrict__ Wt,
    const float* __restrict__ bias0, const float* __restrict__ bias1,
    const float* __restrict__ bias2, const unsigned short* __restrict__ res,
    unsigned short* __restrict__ out0, unsigned short* __restrict__ out1,
    unsigned short* __restrict__ out2) {
  __shared__ short smem[16384];  // 32 KB: buf b at b*8192 (A 4096 | B 4096)
  constexpr int NSTEP = K / 32;
  const int nx = N >> 7;
  const int nwg = gridDim.x;
  const int orig = blockIdx.x;
  const int wgid = (orig & 7) * (nwg >> 3) + (orig >> 3);  // nwg % 8 == 0
  const int m0 = (wgid / nx) * 128, n0 = (wgid % nx) * 128;
  const int t = threadIdx.x;
  const int w = t >> 6, l = t & 63;
  const int wr = (w >> 1) * 64, wc = (w & 1) * 64;
  const int lr = l & 15, lq = l >> 4;
  const int rsw = ((lr >> 1) & 3) << 3;             // read-side XOR (shorts)
  const int srow = w * 32 + (l >> 2);               // staging row within tile
  const int scol = 8 * ((l & 3) ^ ((l >> 3) & 3));  // pre-swizzled source col
  const unsigned short* gA = Ap + (size_t)(m0 + srow) * K + scol;
  const unsigned short* gB = Wt + (size_t)(n0 + srow) * K + scol;
  const int sbo = (w * 32) * 32;                    // wave's staging base (shorts)
  f32x4 acc[4][4] = {};

  auto STAGE = [&](int b, int kt) {
    short* dA = &smem[b * 8192 + sbo];
    short* dB = &smem[b * 8192 + 4096 + sbo];
    const int k0 = kt * 32;
    glld(gA + k0, dA);
    glld(gA + k0 + (size_t)16 * K, dA + 512);
    glld(gB + k0, dB);
    glld(gB + k0 + (size_t)16 * K, dB + 512);
  };

  STAGE(0, 0);
  for (int step = 0; step < NSTEP; step++) {
    const int b = step & 1;
    if (step + 1 < NSTEP) {
      STAGE(b ^ 1, step + 1);
      // drain tile `step`'s 4 loads (FIFO-oldest); keep the 4 new in flight
      asm volatile("s_waitcnt vmcnt(4)" ::: "memory");
    } else {
      asm volatile("s_waitcnt vmcnt(0)" ::: "memory");
    }
    __builtin_amdgcn_s_barrier();
    const short* cA = &smem[b * 8192];
    const short* cB = &smem[b * 8192 + 4096];
    s16x8 af[4], bf[4];
#pragma unroll
    for (int i = 0; i < 4; i++)
      af[i] = *(const s16x8*)&cA[(wr + i * 16 + lr) * 32 + ((lq * 8) ^ rsw)];
#pragma unroll
    for (int i = 0; i < 4; i++)
      bf[i] = *(const s16x8*)&cB[(wc + i * 16 + lr) * 32 + ((lq * 8) ^ rsw)];
#pragma unroll
    for (int i = 0; i < 4; i++)
#pragma unroll
      for (int j2 = 0; j2 < 4; j2++)
        acc[i][j2] = __builtin_amdgcn_mfma_f32_16x16x32_bf16(bf[j2], af[i], acc[i][j2], 0, 0, 0);
    // drain this wave's LDS reads before anyone overwrites this buffer
    asm volatile("s_waitcnt lgkmcnt(0)" ::: "memory");
    __builtin_amdgcn_s_barrier();
  }

  // ---- epilogue. swapped D map: row ml = wr+i*16+lr, cols nl = wc+j2*16+lq*4+r
  short* ot = smem;
  if (EPI == EPI_QKV) {
    const int which = n0 >> 9;  // per-block constant (128-wide tile in 512 region)
    const int ccb = n0 & 511;
    const float* bias = (which == 0) ? bias0 : (which == 1) ? bias1 : bias2;
    unsigned short* dst = (which == 0) ? out0 : (which == 1) ? out1 : out2;
    if (which < 2) {
      // Q/K: LDS-staged fast path with [bh][p][dk] remapped 16B stores
#pragma unroll
      for (int i = 0; i < 4; i++) {
        const int ml = wr + i * 16 + lr;
#pragma unroll
        for (int j2 = 0; j2 < 4; j2++) {
          const int nl = wc + j2 * 16 + lq * 4;
          f32x4 a = acc[i][j2];
          float4 b4 = *(const float4*)&bias[ccb + nl];
          unsigned lo = cvtpk(a[0] + b4.x, a[1] + b4.y);
          unsigned hi = cvtpk(a[2] + b4.z, a[3] + b4.w);
          unsigned* d = (unsigned*)&ot[ml * 128 + ((nl >> 3) ^ (ml & 15)) * 8 + (nl & 7)];
          d[0] = lo; d[1] = hi;
        }
      }
      __syncthreads();
      const int r0 = t >> 1, cb = (t & 1) * 8;
      const int m = m0 + r0;
      const int bi2 = m / PN, p = m % PN;
#pragma unroll
      for (int q = 0; q < 8; q++) {
        int c = cb + q;
        int cc = ccb + c * 8;
        int hh = cc >> 6, dk8 = cc & 63;
        s16x8 vv = *(const s16x8*)&ot[r0 * 128 + ((c ^ (r0 & 15)) * 8)];
        *(s16x8*)&dst[(((size_t)bi2 * H + hh) * PN + p) * DK + dk8] = vv;
      }
    } else {
      // V: transposed per-head [bh][dk][p] scatter (16-lane p-contiguous)
#pragma unroll
      for (int i = 0; i < 4; i++) {
        const int m = m0 + wr + i * 16 + lr;
        const int bi2 = m / PN, p = m % PN;
#pragma unroll
        for (int j2 = 0; j2 < 4; j2++) {
          const int nl = wc + j2 * 16 + lq * 4;
          f32x4 a = acc[i][j2];
#pragma unroll
          for (int r = 0; r < 4; r++) {
            int cc = ccb + nl + r;
            int hh = cc >> 6, dkk = cc & 63;
            dst[(((size_t)bi2 * H + hh) * DK + dkk) * PN + p] = f2b(a[r] + bias[cc]);
          }
        }
      }
    }
  } else {
#pragma unroll
    for (int i = 0; i < 4; i++) {
      const int ml = wr + i * 16 + lr;
#pragma unroll
      for (int j2 = 0; j2 < 4; j2++) {
        const int nl = wc + j2 * 16 + lq * 4;
        f32x4 a = acc[i][j2];
        float4 b4 = *(const float4*)&bias0[n0 + nl];
        float v0 = a[0] + b4.x, v1 = a[1] + b4.y;
        float v2 = a[2] + b4.z, v3 = a[3] + b4.w;
        if (EPI == EPI_GELU) {
          v0 = gelu(v0); v1 = gelu(v1); v2 = gelu(v2); v3 = gelu(v3);
        } else {  // EPI_RES
          s16x4 rr = *(const s16x4*)&res[(size_t)(m0 + ml) * N + n0 + nl];
          v0 += b2f((unsigned short)rr[0]); v1 += b2f((unsigned short)rr[1]);
          v2 += b2f((unsigned short)rr[2]); v3 += b2f((unsigned short)rr[3]);
        }
        unsigned lo = cvtpk(v0, v1), hi = cvtpk(v2, v3);
        unsigned* d = (unsigned*)&ot[ml * 128 + ((nl >> 3) ^ (ml & 15)) * 8 + (nl & 7)];
        d[0] = lo; d[1] = hi;
      }
    }
    __syncthreads();
    const int r0 = t >> 1, cb = (t & 1) * 8;
    const size_t orow = (size_t)(m0 + r0) * N + n0;
#pragma unroll
    for (int q = 0; q < 8; q++) {
      int c = cb + q;
      s16x8 vv = *(const s16x8*)&ot[r0 * 128 + ((c ^ (r0 & 15)) * 8)];
      *(s16x8*)&out0[orow + c * 8] = vv;
    }
  }
}

// ---------------------------------------------------------------------------
// fused attention: scores (+carry,+dm) -> carry write -> softmax -> PV -> O.
// Grid = NB*H*2 (bh = blk>>1, q-half = blk&1), 256 threads = 4 waves (2q x 2k).
// ---------------------------------------------------------------------------
#define PSTR 196
template <int FIRST, int WRITEC>
__global__ __launch_bounds__(256) void k_attn(
    const unsigned short* __restrict__ qb, const unsigned short* __restrict__ kb,
    const unsigned short* __restrict__ vt, const float* __restrict__ dm,
    unsigned short* __restrict__ carry, unsigned short* __restrict__ ob) {
  __shared__ short Ps[96 * PSTR];     // 37.6 KB, unnormalized exp (bf16)
  __shared__ float redmax[2][96];
  __shared__ float redsum[2][96];
  int blk = blockIdx.x;
  int bh = blk >> 1, qh = blk & 1;
  int bi = bh >> 3, h = bh & 7;
  int t = threadIdx.x, w = t >> 6, l = t & 63;
  int wq = w >> 1, wk = w & 1;
  int lr = l & 15, lq = l >> 4, lk = lq * 8;
  const unsigned short* Q = qb + (size_t)bh * PN * DK + (size_t)qh * 96 * DK;
  const unsigned short* K = kb + (size_t)bh * PN * DK;
  f32x4 sv[3][6] = {};
#pragma unroll
  for (int ks = 0; ks < 2; ks++) {
    s16x8 af[3], bf[6];
#pragma unroll
    for (int i = 0; i < 3; i++)
      af[i] = *(const s16x8*)&Q[(size_t)(wq * 48 + i * 16 + lr) * DK + ks * 32 + lk];
#pragma unroll
    for (int j = 0; j < 6; j++)
      bf[j] = *(const s16x8*)&K[(size_t)(wk * 96 + j * 16 + lr) * DK + ks * 32 + lk];
#pragma unroll
    for (int i = 0; i < 3; i++)
#pragma unroll
      for (int j = 0; j < 6; j++)
        sv[i][j] = __builtin_amdgcn_mfma_f32_16x16x32_bf16(af[i], bf[j], sv[i][j], 0, 0, 0);
  }
  size_t cbase = (size_t)blk * 18432 + (size_t)(w * 18) * 256 + (size_t)l * 4;
#pragma unroll
  for (int i = 0; i < 3; i++) {
#pragma unroll
    for (int j = 0; j < 6; j++) {
      s16x4 cv;
      if (!FIRST) cv = *(const s16x4*)&carry[cbase + (i * 6 + j) * 256];
      s16x4 cw;
#pragma unroll
      for (int r = 0; r < 4; r++) {
        int row = qh * 96 + wq * 48 + i * 16 + lq * 4 + r;
        int col = wk * 96 + j * 16 + lr;
        float v = sv[i][j][r] * SCALE + dm[row * PN + col];
        if (!FIRST) v += b2f((unsigned short)cv[r]);
        if (WRITEC) cw[r] = (short)f2b(v);
        sv[i][j][r] = v;
      }
      if (WRITEC) *(s16x4*)&carry[cbase + (i * 6 + j) * 256] = cw;
    }
  }
#pragma unroll
  for (int i = 0; i < 3; i++) {
#pragma unroll
    for (int r = 0; r < 4; r++) {
      float m = sv[i][0][r];
#pragma unroll
      for (int j = 1; j < 6; j++) m = fmaxf(m, sv[i][j][r]);
#pragma unroll
      for (int off = 1; off < 16; off <<= 1) m = fmaxf(m, __shfl_xor(m, off));
      if (lr == 0) redmax[wk][wq * 48 + i * 16 + lq * 4 + r] = m;
    }
  }
  __syncthreads();
#pragma unroll
  for (int i = 0; i < 3; i++) {
#pragma unroll
    for (int r = 0; r < 4; r++) {
      int row = wq * 48 + i * 16 + lq * 4 + r;
      float fm = fmaxf(redmax[0][row], redmax[1][row]);
      float sum = 0.f;
#pragma unroll
      for (int j = 0; j < 6; j++) {
        float e = __expf(sv[i][j][r] - fm);
        sum += e;
        Ps[row * PSTR + wk * 96 + j * 16 + lr] = f2b(e);
      }
#pragma unroll
      for (int off = 1; off < 16; off <<= 1) sum += __shfl_xor(sum, off);
      if (lr == 0) redsum[wk][row] = sum;
    }
  }
  __syncthreads();
  const unsigned short* V = vt + (size_t)bh * DK * PN;
  f32x4 po[3][2] = {};
#pragma unroll
  for (int ks = 0; ks < 6; ks++) {
    s16x8 af[3], bf[2];
#pragma unroll
    for (int i = 0; i < 3; i++)
      af[i] = *(const s16x8*)&Ps[(wq * 48 + i * 16 + lr) * PSTR + ks * 32 + lk];
#pragma unroll
    for (int j = 0; j < 2; j++)
      bf[j] = *(const s16x8*)&V[(size_t)(wk * 32 + j * 16 + lr) * PN + ks * 32 + lk];
#pragma unroll
    for (int i = 0; i < 3; i++)
#pragma unroll
      for (int j = 0; j < 2; j++)
        po[i][j] = __builtin_amdgcn_mfma_f32_16x16x32_bf16(af[i], bf[j], po[i][j], 0, 0, 0);
  }
#pragma unroll
  for (int i = 0; i < 3; i++) {
#pragma unroll
    for (int r = 0; r < 4; r++) {
      int row = wq * 48 + i * 16 + lq * 4 + r;
      float inv = 1.0f / (redsum[0][row] + redsum[1][row]);
#pragma unroll
      for (int j = 0; j < 2; j++) {
        int dk = wk * 32 + j * 16 + lr;
        ob[((size_t)bi * PN + qh * 96 + row) * D + h * 64 + dk] = f2b(po[i][j][r] * inv);
      }
    }
  }
}

// ---------------------------------------------------------------------------
// LayerNorm: bf16 in -> bf16 out. One wave per row, s16x8 I/O (16B/lane).
// ---------------------------------------------------------------------------
__global__ __launch_bounds__(256) void k_ln(
    const unsigned short* __restrict__ in, const float* __restrict__ g,
    const float* __restrict__ b, unsigned short* __restrict__ out) {
  int r = blockIdx.x * 4 + (threadIdx.x >> 6);
  int l = threadIdx.x & 63;
  const unsigned short* x = in + (size_t)r * D + l * 8;
  s16x8 xv = *(const s16x8*)x;
  float v[8], sm = 0.f, sq = 0.f;
#pragma unroll
  for (int j = 0; j < 8; j++) {
    v[j] = b2f((unsigned short)xv[j]);
    sm += v[j];
    sq += v[j] * v[j];
  }
#pragma unroll
  for (int off = 32; off > 0; off >>= 1) {
    sm += __shfl_xor(sm, off);
    sq += __shfl_xor(sq, off);
  }
  float mu = sm * (1.0f / D);
  float rs = rsqrtf(sq * (1.0f / D) - mu * mu + 1e-5f);
  float4 g0 = *(const float4*)&g[l * 8], g1 = *(const float4*)&g[l * 8 + 4];
  float4 b0 = *(const float4*)&b[l * 8], b1 = *(const float4*)&b[l * 8 + 4];
  float gg[8] = {g0.x, g0.y, g0.z, g0.w, g1.x, g1.y, g1.z, g1.w};
  float bb[8] = {b0.x, b0.y, b0.z, b0.w, b1.x, b1.y, b1.z, b1.w};
  s16x8 ov;
#pragma unroll
  for (int j = 0; j < 8; j++) ov[j] = (short)f2b(gg[j] * (v[j] - mu) * rs + bb[j]);
  *(s16x8*)(out + (size_t)r * D + l * 8) = ov;
}

// ---------------------------------------------------------------------------
// head input transpose (bf16): xo[bv][d*PN+p] = s[bv*PN+p][d]
// ---------------------------------------------------------------------------
__global__ __launch_bounds__(256) void k_transpose_b(
    const unsigned short* __restrict__ sb, unsigned short* __restrict__ xo) {
  __shared__ unsigned short tile[32][33];
  int d0 = blockIdx.x * 32, p0 = blockIdx.y * 32, bv = blockIdx.z;
  int tx = threadIdx.x & 31, ty = threadIdx.x >> 5;
#pragma unroll
  for (int i = 0; i < 4; i++)
    tile[ty + 8 * i][tx] = sb[((size_t)bv * PN + p0 + ty + 8 * i) * D + d0 + tx];
  __syncthreads();
#pragma unroll
  for (int i = 0; i < 4; i++)
    xo[(size_t)bv * NF + (size_t)(d0 + ty + 8 * i) * PN + p0 + tx] = tile[tx][ty + 8 * i];
}

// ---------------------------------------------------------------------------
// head MFMA GEMM, split-K partials
// ---------------------------------------------------------------------------
__global__ __launch_bounds__(448) void k_head_mgemm(
    const unsigned short* __restrict__ A, const unsigned short* __restrict__ B,
    float* __restrict__ pp) {
  __shared__ short As[112 * 40];
  __shared__ short Bs[336 * 40];
  int kc = blockIdx.x;
  int t = threadIdx.x, w = t >> 6, l = t & 63;
  int lr = l & 15, lk = (l >> 4) * 8;
  int ar = t >> 2, ac = (t & 3) * 8;
  f32x4 acc[7][3] = {};
  for (int ks = 0; ks < 24; ks++) {
    int k0 = kc * 768 + ks * 32;
    s16x8 av = *(const s16x8*)&A[(size_t)ar * NF + k0 + ac];
    s16x8 bv0, bv1, bv2;
    {
      int i0 = t, i1 = t + 448, i2 = t + 896;
      bv0 = *(const s16x8*)&B[(size_t)(i0 >> 2) * NF + k0 + (i0 & 3) * 8];
      bv1 = *(const s16x8*)&B[(size_t)(i1 >> 2) * NF + k0 + (i1 & 3) * 8];
      bv2 = *(const s16x8*)&B[(size_t)(i2 >> 2) * NF + k0 + (i2 & 3) * 8];
    }
    __syncthreads();
    *(s16x8*)&As[ar * 40 + ac] = av;
    *(s16x8*)&Bs[(t >> 2) * 40 + (t & 3) * 8] = bv0;
    *(s16x8*)&Bs[((t + 448) >> 2) * 40 + (t & 3) * 8] = bv1;
    *(s16x8*)&Bs[((t + 896) >> 2) * 40 + (t & 3) * 8] = bv2;
    __syncthreads();
    s16x8 bf[3];
#pragma unroll
    for (int j = 0; j < 3; j++)
      bf[j] = *(const s16x8*)&Bs[((w * 3 + j) * 16 + lr) * 40 + lk];
#pragma unroll
    for (int mf = 0; mf < 7; mf++) {
      s16x8 af = *(const s16x8*)&As[(mf * 16 + lr) * 40 + lk];
#pragma unroll
      for (int j = 0; j < 3; j++)
        acc[mf][j] = __builtin_amdgcn_mfma_f32_16x16x32_bf16(af, bf[j], acc[mf][j], 0, 0, 0);
    }
  }
#pragma unroll
  for (int mf = 0; mf < 7; mf++) {
#pragma unroll
    for (int j = 0; j < 3; j++) {
#pragma unroll
      for (int r = 0; r < 4; r++) {
        int row = mf * 16 + (l >> 4) * 4 + r;
        int col = (w * 3 + j) * 16 + lr;
        pp[((size_t)kc * NB + row) * TW + col] = acc[mf][j][r];
      }
    }
  }
}

__global__ __launch_bounds__(256) void k_head_reduce(
    const float* __restrict__ pp, const float* __restrict__ bh,
    float* __restrict__ out) {
  int i = blockIdx.x * 256 + threadIdx.x;
  float s = bh[i % TW];
  for (int kc = 0; kc < 128; kc++) s += pp[(size_t)kc * (NB * TW) + i];
  out[i] = s;
}

// ---------------------------------------------------------------------------
extern "C" void kernel_launch(void* const* d_in, const int* in_sizes, int n_in,
                              void* d_out, int out_size, void* d_ws, size_t ws_size,
                              hipStream_t stream) {
  const float* z     = (const float*)d_in[0];
  const float* W_P   = (const float*)d_in[1];
  const float* b_P   = (const float*)d_in[2];
  const float* W_pos = (const float*)d_in[3];
  const float* Wq    = (const float*)d_in[4];
  const float* bq    = (const float*)d_in[5];
  const float* Wk    = (const float*)d_in[6];
  const float* bk    = (const float*)d_in[7];
  const float* Wv    = (const float*)d_in[8];
  const float* bv    = (const float*)d_in[9];
  const float* Wo    = (const float*)d_in[10];
  const float* bo    = (const float*)d_in[11];
  const float* ln1g  = (const float*)d_in[12];
  const float* ln1b  = (const float*)d_in[13];
  const float* W1    = (const float*)d_in[14];
  const float* b1    = (const float*)d_in[15];
  const float* W2    = (const float*)d_in[16];
  const float* b2    = (const float*)d_in[17];
  const float* ln2g  = (const float*)d_in[18];
  const float* ln2b  = (const float*)d_in[19];
  const float* Wh    = (const float*)d_in[20];
  const float* bh    = (const float*)d_in[21];
  const float* dmask = (const float*)d_in[22];
  float* out = (float*)d_out;

  // ---- workspace layout (bytes), extent 217,055,232 ----
  char* ws = (char*)d_ws;
  unsigned short* s  = (unsigned short*)ws;
  unsigned short* sc = (unsigned short*)(ws + 22020096ull);
  unsigned short* qb = (unsigned short*)(ws + 88080384ull);
  unsigned short* kb = (unsigned short*)(ws + 110100480ull);
  unsigned short* vb = (unsigned short*)(ws + 132120576ull);
  unsigned short* ob = (unsigned short*)(ws + 154140672ull);
  unsigned short* tb = (unsigned short*)(ws + 176160768ull);
  unsigned short* hb = qb;                       // 88MB (qb..ob), post-attention
  unsigned short* t2 = tb;                       // FFN out reuses tb region
  unsigned short* wt = (unsigned short*)(ws + 198180864ull);
  const size_t WLS = 3145728;  // shorts per layer block
  // head-phase reuse:
  unsigned short* xo  = (unsigned short*)(ws + 88080384ull);   // [112][98304]
  unsigned short* Wht = (unsigned short*)(ws + 110100480ull);  // [336][98304]
  float* pp = (float*)(ws + 22020096ull);                      // [128][112][336]

  k_patch_embed<<<RTOT, 256, 0, stream>>>(z, W_P, b_P, W_pos, s);

  // pre-loop batched weight transposes (z = layer)
  k_wtz<<<dim3(16, 16, 3), 256, 0, stream>>>(Wq, wt + 0,       D, D,   262144, WLS);
  k_wtz<<<dim3(16, 16, 3), 256, 0, stream>>>(Wk, wt + 262144,  D, D,   262144, WLS);
  k_wtz<<<dim3(16, 16, 3), 256, 0, stream>>>(Wv, wt + 524288,  D, D,   262144, WLS);
  k_wtz<<<dim3(16, 16, 3), 256, 0, stream>>>(Wo, wt + 786432,  D, D,   262144, WLS);
  k_wtz<<<dim3(64, 16, 3), 256, 0, stream>>>(W1, wt + 1048576, D, DFF, 1048576, WLS);
  k_wtz<<<dim3(16, 64, 3), 256, 0, stream>>>(W2, wt + 2097152, DFF, D, 1048576, WLS);

  for (int l = 0; l < LYR; l++) {
    unsigned short* wtL = wt + (size_t)l * WLS;
    unsigned short* wqkv_t = wtL;
    unsigned short* wo_t   = wtL + 786432;
    unsigned short* w1_t   = wtL + 1048576;
    unsigned short* w2_t   = wtL + 2097152;

    // fused QKV GEMM: [21504,512] x [512,1536], grid 12x168 = 2016
    k_mgemm<EPI_QKV, 1536, 512><<<2016, 256, 0, stream>>>(
        s, wqkv_t, bq + l * D, bk + l * D, bv + l * D, nullptr, qb, kb, vb);
    // fused attention (scores + carry + softmax + PV)
    const float* dm = dmask + (size_t)l * PN * PN;
    if (l == 0)
      k_attn<1, 1><<<NB * H * 2, 256, 0, stream>>>(qb, kb, vb, dm, sc, ob);
    else if (l == LYR - 1)
      k_attn<0, 0><<<NB * H * 2, 256, 0, stream>>>(qb, kb, vb, dm, sc, ob);
    else
      k_attn<0, 1><<<NB * H * 2, 256, 0, stream>>>(qb, kb, vb, dm, sc, ob);
    // O-proj + residual: grid 4x168 = 672
    k_mgemm<EPI_RES, 512, 512><<<672, 256, 0, stream>>>(
        ob, wo_t, bo + l * D, nullptr, nullptr, s, tb, nullptr, nullptr);
    k_ln<<<RTOT / 4, 256, 0, stream>>>(tb, ln1g + l * D, ln1b + l * D, s);
    // FFN full-M: W1 grid 2688, W2 grid 672
    k_mgemm<EPI_GELU, 2048, 512><<<2688, 256, 0, stream>>>(
        s, w1_t, b1 + l * DFF, nullptr, nullptr, nullptr, hb, nullptr, nullptr);
    k_mgemm<EPI_RES, 512, 2048><<<672, 256, 0, stream>>>(
        hb, w2_t, b2 + l * D, nullptr, nullptr, s, t2, nullptr, nullptr);
    k_ln<<<RTOT / 4, 256, 0, stream>>>(t2, ln2g + l * D, ln2b + l * D, s);
  }

  // head: pack Wh^T bf16, transpose s -> xo bf16, split-K MFMA, reduce
  k_wtz<<<dim3(11, 3072, 1), 256, 0, stream>>>(Wh, Wht, NF, TW, 0, 0);
  k_transpose_b<<<dim3(16, 6, NB), 256, 0, stream>>>(s, xo);
  k_head_mgemm<<<128, 448, 0, stream>>>(xo, Wht, pp);
  k_head_reduce<<<147, 256, 0, stream>>>(pp, bh, out);
}